// Round 4
// baseline (47.280 us; speedup 1.0000x reference)
//
#include <hip/hip_runtime.h>
#include <math.h>

#define NB 768
#define ND 128
#define NC 12            // NB / 64 lane-chunks
#define APB 4            // anchors per block (= waves per block)
#define TL_MARGIN 1.0f
#define TL_EPS 1e-12f

// d_ws layout: float psum[NB]; float pcnt[NB];

__global__ __launch_bounds__(256) void triplet_batch_kernel(
    const float* __restrict__ E, const int* __restrict__ L,
    float* __restrict__ psum, float* __restrict__ pcnt)
{
    __shared__ float arow[APB][ND];     // 2 KB
    __shared__ float drows[APB][NB];    // 12 KB
    __shared__ int   lbl[NB];           // 3 KB
    __shared__ float s_sqi[APB];

    const int i0   = blockIdx.x * APB;
    const int tid  = threadIdx.x;
    const int lane = tid & 63;
    const int wave = tid >> 6;

    // stage labels + the 4 anchor rows (coalesced)
    for (int j = tid; j < NB; j += 256) lbl[j] = L[j];
    for (int idx = tid; idx < APB * ND; idx += 256) {
        int a = idx >> 7, k = idx & 127;
        arow[a][k] = E[(size_t)(i0 + a) * ND + k];
    }
    __syncthreads();

    // wave w computes sq(anchor w) via shuffle reduce
    {
        float v0 = arow[wave][lane];
        float v1 = arow[wave][lane + 64];
        float s = v0 * v0 + v1 * v1;
        #pragma unroll
        for (int off = 32; off > 0; off >>= 1) s += __shfl_xor(s, off);
        if (lane == 0) s_sqi[wave] = s;
    }
    __syncthreads();

    // ---- distance phase, coalesced k-split ----
    // lane = r*16 + g : r = row-within-group-of-4, g = k-group (16 x float4)
    const int r = lane >> 4;
    const int g = lane & 15;

    // preload anchor fragments for this lane's k positions (static indexing)
    float4 afr[2][APB];
    #pragma unroll
    for (int i = 0; i < 2; ++i)
        #pragma unroll
        for (int a = 0; a < APB; ++a)
            afr[i][a] = *(const float4*)&arow[a][(i * 16 + g) * 4];

    // wave handles j in [wave*192, wave*192+192), 4 rows per group
    #pragma unroll 4
    for (int grp = 0; grp < 48; ++grp) {
        const int j = wave * 192 + grp * 4 + r;
        const float4* ejp = (const float4*)(E + (size_t)j * ND);
        float d0 = 0.f, d1 = 0.f, d2 = 0.f, d3 = 0.f, sj = 0.f;
        #pragma unroll
        for (int i = 0; i < 2; ++i) {
            float4 v = ejp[i * 16 + g];           // 16 lanes/row contiguous
            sj += v.x * v.x + v.y * v.y + v.z * v.z + v.w * v.w;
            float4 a0 = afr[i][0], a1 = afr[i][1], a2 = afr[i][2], a3 = afr[i][3];
            d0 += a0.x * v.x + a0.y * v.y + a0.z * v.z + a0.w * v.w;
            d1 += a1.x * v.x + a1.y * v.y + a1.z * v.z + a1.w * v.w;
            d2 += a2.x * v.x + a2.y * v.y + a2.z * v.z + a2.w * v.w;
            d3 += a3.x * v.x + a3.y * v.y + a3.z * v.z + a3.w * v.w;
        }
        // butterfly over the 16 g-lanes (low 4 lane bits)
        #pragma unroll
        for (int off = 1; off < 16; off <<= 1) {
            d0 += __shfl_xor(d0, off);
            d1 += __shfl_xor(d1, off);
            d2 += __shfl_xor(d2, off);
            d3 += __shfl_xor(d3, off);
            sj += __shfl_xor(sj, off);
        }
        if (g < APB) {                             // lane g writes anchor g
            float dsel = (g == 0) ? d0 : (g == 1) ? d1 : (g == 2) ? d2 : d3;
            float d2v  = s_sqi[g] + sj - 2.f * dsel;
            drows[g][j] = sqrtf(fmaxf(d2v, TL_EPS));
        }
    }
    __syncthreads();

    // ---- mining: wave w mines anchor i0+w, fully wave-local ----
    const int a  = wave;
    const int ia = i0 + a;
    const int li = lbl[ia];

    float dk[NC];
    unsigned negm = 0u, posm = 0u;
    #pragma unroll
    for (int c = 0; c < NC; ++c) {
        int j = c * 64 + lane;
        dk[c] = drows[a][j];
        int lj = lbl[j];
        if (lj != li)     negm |= (1u << c);
        else if (j != ia) posm |= (1u << c);
    }

    // hardest-negative VALUE (min over negatives)
    float bv = INFINITY;
    #pragma unroll
    for (int c = 0; c < NC; ++c)
        if ((negm >> c) & 1u) bv = fminf(bv, dk[c]);
    #pragma unroll
    for (int off = 32; off > 0; off >>= 1)
        bv = fminf(bv, __shfl_xor(bv, off));
    const float hval = bv;

    // semi-hard mining: first k with (neg && pd < dk < pd+margin), else hval
    float lsum = 0.f, lcnt = 0.f;
    if (isfinite(hval)) {
        #pragma unroll 1
        for (int c = 0; c < NC; ++c) {
            unsigned long long pm = __ballot((posm >> c) & 1u);
            while (pm) {
                const int sl = __builtin_ctzll(pm);
                pm &= pm - 1;
                const float pd = __shfl(dk[c], sl);
                float nd = hval;
                #pragma unroll 1
                for (int c2 = 0; c2 < NC; ++c2) {
                    bool pred = ((negm >> c2) & 1u) &&
                                (dk[c2] > pd) && (dk[c2] < pd + TL_MARGIN);
                    unsigned long long m = __ballot(pred);
                    if (m) { nd = __shfl(dk[c2], __builtin_ctzll(m)); break; }
                }
                lsum += fmaxf(pd - nd + TL_MARGIN, 0.f);
                lcnt += 1.f;
            }
        }
    }
    if (lane == 0) { psum[ia] = lsum; pcnt[ia] = lcnt; }
}

__global__ __launch_bounds__(64) void triplet_finalize_kernel(
    const float* __restrict__ psum, const float* __restrict__ pcnt,
    float* __restrict__ out)
{
    const int lane = threadIdx.x;
    float a = 0.f, b = 0.f;
    for (int j = lane; j < NB; j += 64) { a += psum[j]; b += pcnt[j]; }
    #pragma unroll
    for (int off = 32; off > 0; off >>= 1) {
        a += __shfl_xor(a, off);
        b += __shfl_xor(b, off);
    }
    if (lane == 0) out[0] = a / fmaxf(b, 1.f);
}

extern "C" void kernel_launch(void* const* d_in, const int* in_sizes, int n_in,
                              void* d_out, int out_size, void* d_ws, size_t ws_size,
                              hipStream_t stream) {
    const float* E = (const float*)d_in[0];
    const int*   L = (const int*)d_in[1];
    float* psum = (float*)d_ws;
    float* pcnt = psum + NB;
    float* out  = (float*)d_out;

    triplet_batch_kernel<<<NB / APB, 256, 0, stream>>>(E, L, psum, pcnt);
    triplet_finalize_kernel<<<1, 64, 0, stream>>>(psum, pcnt, out);
}